// Round 7
// baseline (531.933 us; speedup 1.0000x reference)
//
#include <hip/hip_runtime.h>
#include <hip/hip_fp16.h>

#define NCH 21
#define NCH2 22         // 21 Q-channels + channel 21 = weight-sum (norm)
#define VSH 32          // value row stride in halves (64B line)
#define QSH 32          // Q row stride in halves (64B line)
#define USH 24          // -U row stride in halves (48B, 16B-aligned)
#define NPIX (512*512)  // 2^18
#define SEG 192         // pairs per gather segment (multiple of 12)
#define DECODE (1.0f/(16383.f*128.f))

// ---------------- wave-aggregated atomic rank ----------------
__device__ __forceinline__ int wave_rank_atomic(int m, bool valid, int* __restrict__ cur) {
  int lane = threadIdx.x & 63;
  unsigned long long todo = __ballot(valid);
  int out = 0;
  while (todo) {
    int leader = __ffsll((unsigned long long)todo) - 1;
    int lm = __shfl(m, leader);
    unsigned long long match = __ballot(valid && (m == lm));
    int cnt = __popcll(match);
    int b = 0;
    if (lane == leader) b = atomicAdd(&cur[lm], cnt);
    b = __shfl(b, leader);
    if (valid && (m == lm)) out = b + __popcll(match & ((1ull << lane) - 1ull));
    todo &= ~match;
  }
  return out;
}

// ---------------- unified CSR build (slab order: t = j*NPIX + n) ----------------

__global__ void count_fused_kernel(const int* __restrict__ os_b, const int* __restrict__ os_s,
                                   int* __restrict__ cnt, int nptot, int Mb) {
  int t = blockIdx.x*blockDim.x + threadIdx.x;
  bool valid = (t < nptot);
  int m = 0;
  if (valid) {
    if (t < 6*NPIX) { int j = t >> 18, n = t & (NPIX-1); m = os_b[n*6+j]; }
    else { int t2 = t - 6*NPIX; int j = t2 >> 18, n = t2 & (NPIX-1); m = Mb + os_s[n*3+j]; }
  }
  int lane = threadIdx.x & 63;
  unsigned long long todo = __ballot(valid);
  while (todo) {
    int leader = __ffsll((unsigned long long)todo) - 1;
    int lm = __shfl(m, leader);
    unsigned long long match = __ballot(valid && (m == lm));
    if (lane == leader) atomicAdd(&cnt[lm], __popcll(match));
    todo &= ~match;
  }
}

__global__ void scan_block_kernel(const int* __restrict__ cnt, int* __restrict__ excl,
                                  int* __restrict__ bsum, int M) {
  __shared__ int s[256];
  int i = blockIdx.x*256 + threadIdx.x;
  int v = (i < M) ? cnt[i] : 0;
  s[threadIdx.x] = v;
  __syncthreads();
  for (int off = 1; off < 256; off <<= 1) {
    int t = (threadIdx.x >= off) ? s[threadIdx.x - off] : 0;
    __syncthreads();
    s[threadIdx.x] += t;
    __syncthreads();
  }
  if (i < M) excl[i] = s[threadIdx.x] - v;
  if (threadIdx.x == 255) bsum[blockIdx.x] = s[255];
}

__global__ void scan_sums_kernel(int* __restrict__ bsum, int nb) {
  __shared__ int s[256];
  __shared__ int carry;
  if (threadIdx.x == 0) carry = 0;
  __syncthreads();
  for (int base = 0; base < nb; base += 256) {
    int i = base + threadIdx.x;
    int v = (i < nb) ? bsum[i] : 0;
    s[threadIdx.x] = v;
    __syncthreads();
    for (int off = 1; off < 256; off <<= 1) {
      int t = (threadIdx.x >= off) ? s[threadIdx.x - off] : 0;
      __syncthreads();
      s[threadIdx.x] += t;
      __syncthreads();
    }
    if (i < nb) bsum[i] = s[threadIdx.x] - v + carry;
    int tot = s[255];
    __syncthreads();
    if (threadIdx.x == 0) carry += tot;
    __syncthreads();
  }
  if (threadIdx.x == 0) bsum[nb] = carry;   // grand total
}

__global__ void scan_add_kernel(int* __restrict__ excl, const int* __restrict__ bsum,
                                int M, int nb) {
  int i = blockIdx.x*blockDim.x + threadIdx.x;
  if (i < M) excl[i] += bsum[i >> 8];
  else if (i == M) excl[M] = bsum[nb];
}

__global__ void fill_fused_kernel(const int* __restrict__ os_b, const float* __restrict__ ws_b,
                                  const int* __restrict__ os_s, const float* __restrict__ ws_s,
                                  const int* __restrict__ start, int* __restrict__ cur,
                                  unsigned int* __restrict__ pw, int nptot, int Mb) {
  int t = blockIdx.x*blockDim.x + threadIdx.x;
  bool valid = (t < nptot);
  int m = 0, pix = 0; float w = 0.f;
  if (valid) {
    if (t < 6*NPIX) { int j = t >> 18, n = t & (NPIX-1); m = os_b[n*6+j]; pix = n; w = ws_b[n*6+j]; }
    else { int t2 = t - 6*NPIX; int j = t2 >> 18, n = t2 & (NPIX-1);
           m = Mb + os_s[n*3+j]; pix = n; w = ws_s[n*3+j]; }
  }
  int slot = wave_rank_atomic(m, valid, cur);
  if (valid) {
    int w14 = (int)(w * 16383.f + 0.5f);
    w14 = w14 < 0 ? 0 : (w14 > 16383 ? 16383 : w14);
    pw[start[m] + slot] = ((unsigned int)pix << 14) | (unsigned int)w14;
  }
}

// ---------------- segment table ----------------

__global__ void nseg_kernel(const int* __restrict__ start, int* __restrict__ segcnt, int Mtot) {
  int m = blockIdx.x*blockDim.x + threadIdx.x;
  if (m >= Mtot) return;
  int len = start[m+1] - start[m];
  segcnt[m] = (len + SEG - 1) / SEG;
}

__global__ void seg_fill_kernel(const int* __restrict__ segstart, int* __restrict__ seg_m, int Mtot) {
  int m = blockIdx.x*blockDim.x + threadIdx.x;
  if (m >= Mtot) return;
  int b = segstart[m], e = segstart[m+1];
  for (int s = b; s < e; ++s) seg_m[s] = m;
}

// ---------------- lattice ops ----------------

// segmented gather: wave per segment, 3 pair-groups x 21 channels, fp32 partials
__global__ void gather_seg_kernel(const __half* __restrict__ Qh, const int* __restrict__ start,
                                  const int* __restrict__ segstart, const int* __restrict__ seg_m,
                                  const unsigned int* __restrict__ pw,
                                  float* __restrict__ partials, int Mtot) {
  int wid = blockIdx.x*(blockDim.x >> 6) + (threadIdx.x >> 6);
  int NSEG = segstart[Mtot];
  if (wid >= NSEG) return;
  int m = seg_m[wid];
  int k0 = start[m] + (wid - segstart[m])*SEG;
  int k1 = start[m+1];
  if (k1 > k0 + SEG) k1 = k0 + SEG;
  int lane = threadIdx.x & 63;
  int pg = lane / 21;
  int c  = lane - pg*21;
  float s = 0.f, wsum = 0.f;
  if (pg < 3) {
    int k = k0 + pg;
    for (; k + 9 < k1; k += 12) {
      unsigned int a0 = pw[k], a1 = pw[k+3], a2 = pw[k+6], a3 = pw[k+9];
      float w0 = (float)(a0 & 16383u), w1 = (float)(a1 & 16383u);
      float w2 = (float)(a2 & 16383u), w3 = (float)(a3 & 16383u);
      s += w0 * __half2float(Qh[((size_t)(a0 >> 14) << 5) + c])
         + w1 * __half2float(Qh[((size_t)(a1 >> 14) << 5) + c])
         + w2 * __half2float(Qh[((size_t)(a2 >> 14) << 5) + c])
         + w3 * __half2float(Qh[((size_t)(a3 >> 14) << 5) + c]);
      wsum += w0 + w1 + w2 + w3;
    }
    for (; k < k1; k += 3) {
      unsigned int a = pw[k];
      float w = (float)(a & 16383u);
      s += w * __half2float(Qh[((size_t)(a >> 14) << 5) + c]);
      wsum += w;
    }
  }
  float s1 = __shfl(s, (lane + 21) & 63);
  float s2 = __shfl(s, (lane + 42) & 63);
  float wt = __shfl(wsum, 0) + __shfl(wsum, 21) + __shfl(wsum, 42);
  float* row = partials + (size_t)wid*NCH2;
  if (lane < 21)       row[c]  = s + s1 + s2;
  else if (lane == 21) row[21] = wt;
}

// combine segment partials -> fp16 value rows (coalesced across c)
__global__ void combine_kernel(const float* __restrict__ partials,
                               const int* __restrict__ segstart,
                               __half* __restrict__ valsB, __half* __restrict__ valsS,
                               int Mb, int Mtot) {
  int t = blockIdx.x*blockDim.x + threadIdx.x;
  if (t >= Mtot*NCH2) return;
  int m = t / NCH2, c = t - m*NCH2;
  int s0 = segstart[m], s1 = segstart[m+1];
  float acc = 0.f;
  int s = s0;
  for (; s + 3 < s1; s += 4)
    acc += partials[(size_t)s*NCH2+c] + partials[(size_t)(s+1)*NCH2+c]
         + partials[(size_t)(s+2)*NCH2+c] + partials[(size_t)(s+3)*NCH2+c];
  for (; s < s1; ++s) acc += partials[(size_t)s*NCH2+c];
  __half* row = (m < Mb) ? (valsB + (size_t)(m+1)*VSH) : (valsS + (size_t)(m-Mb+1)*VSH);
  row[c] = __float2half(acc * DECODE);
}

// blur on fp16 rows, half2 chunks (11 chunks = 22 channels), fp32 math
__global__ void blurH_fused_kernel(const __half* __restrict__ inB, __half* __restrict__ outB,
                                   const int* __restrict__ bnB, int Mb,
                                   const __half* __restrict__ inS, __half* __restrict__ outS,
                                   const int* __restrict__ bnS, int Ms) {
  int t = blockIdx.x*blockDim.x + threadIdx.x;
  const __half* in; __half* out; const int* bn; int i, j;
  int tb = Mb*11;
  if (t < tb) { i = t/11; j = t - i*11; in = inB; out = outB; bn = bnB; }
  else {
    int t2 = t - tb;
    if (t2 >= Ms*11) return;
    i = t2/11; j = t2 - i*11; in = inS; out = outS; bn = bnS;
  }
  int b0 = bn[2*i], b1 = bn[2*i+1];
  float2 a = __half22float2(((const __half2*)(in + (size_t)(i+1)*VSH))[j]);
  float2 x = __half22float2(((const __half2*)(in + (size_t)b0*VSH))[j]);
  float2 y = __half22float2(((const __half2*)(in + (size_t)b1*VSH))[j]);
  float2 o;
  o.x = a.x + 0.5f*(x.x + y.x);
  o.y = a.y + 0.5f*(x.y + y.y);
  ((__half2*)(out + (size_t)(i+1)*VSH))[j] = __float22half2_rn(o);
}

// ---------------- pixel-side kernels ----------------

__global__ void softmax_init_kernel(const float* __restrict__ U, __half* __restrict__ Qh,
                                    __half* __restrict__ Uh) {
  int n = blockIdx.x*blockDim.x + threadIdx.x;
  if (n >= NPIX) return;
  float l[NCH];
  float m = -3.4e38f;
  #pragma unroll
  for (int c = 0; c < NCH; ++c) {
    l[c] = -U[(size_t)n*NCH+c];
    Uh[(size_t)n*USH+c] = __float2half(l[c]);   // store negated U
    m = fmaxf(m, l[c]);
  }
  float s = 0.f;
  #pragma unroll
  for (int c = 0; c < NCH; ++c) { l[c] = expf(l[c]-m); s += l[c]; }
  float r = 1.0f/s;
  #pragma unroll
  for (int c = 0; c < NCH; ++c) Qh[(size_t)n*QSH+c] = __float2half(l[c]*r);
}

template<bool FINAL>
__global__ void slice_combine_softmax_kernel(
    const __half* __restrict__ Uh,
    const __half* __restrict__ vb, const __half* __restrict__ vs,
    const float* __restrict__ ws_b, const int* __restrict__ os_b,
    const float* __restrict__ ws_s, const int* __restrict__ os_s,
    float* __restrict__ QoutF, __half* __restrict__ QoutH) {
  int n = blockIdx.x*blockDim.x + threadIdx.x;
  if (n >= NPIX) return;
  float l[NCH];
  #pragma unroll
  for (int c = 0; c < NCH; ++c) l[c] = __half2float(Uh[(size_t)n*USH+c]);
  float acc[NCH2];
  #pragma unroll
  for (int c = 0; c < NCH2; ++c) acc[c] = 0.f;
  #pragma unroll
  for (int j = 0; j < 6; ++j) {
    float w = ws_b[n*6+j];
    const __half* v = vb + (size_t)(os_b[n*6+j]+1)*VSH;
    #pragma unroll
    for (int c = 0; c < NCH2; ++c) acc[c] += w*__half2float(v[c]);
  }
  float rb = 10.0f/(acc[NCH] + 1e-12f);
  #pragma unroll
  for (int c = 0; c < NCH; ++c) l[c] += rb*acc[c];
  #pragma unroll
  for (int c = 0; c < NCH2; ++c) acc[c] = 0.f;
  #pragma unroll
  for (int j = 0; j < 3; ++j) {
    float w = ws_s[n*3+j];
    const __half* v = vs + (size_t)(os_s[n*3+j]+1)*VSH;
    #pragma unroll
    for (int c = 0; c < NCH2; ++c) acc[c] += w*__half2float(v[c]);
  }
  float rs = 3.0f/(acc[NCH] + 1e-12f);
  #pragma unroll
  for (int c = 0; c < NCH; ++c) l[c] += rs*acc[c];
  float m = -3.4e38f;
  #pragma unroll
  for (int c = 0; c < NCH; ++c) m = fmaxf(m, l[c]);
  float s = 0.f;
  #pragma unroll
  for (int c = 0; c < NCH; ++c) { l[c] = expf(l[c]-m); s += l[c]; }
  float r = 1.0f/s;
  if (FINAL) {
    #pragma unroll
    for (int c = 0; c < NCH; ++c) QoutF[(size_t)n*NCH+c] = l[c]*r;
  } else {
    #pragma unroll
    for (int c = 0; c < NCH; ++c) QoutH[(size_t)n*QSH+c] = __float2half(l[c]*r);
  }
}

// ---------------- host ----------------

extern "C" void kernel_launch(void* const* d_in, const int* in_sizes, int n_in,
                              void* d_out, int out_size, void* d_ws, size_t ws_size,
                              hipStream_t stream) {
  const float* U    = (const float*)d_in[0];
  const float* ws_b = (const float*)d_in[1];
  const float* ws_s = (const float*)d_in[2];
  const int*   os_b = (const int*)d_in[3];
  const int*   os_s = (const int*)d_in[4];
  const int*   bn_b = (const int*)d_in[5];
  const int*   bn_s = (const int*)d_in[6];
  const int Mb = in_sizes[5] / 12;
  const int Ms = in_sizes[6] / 6;
  const int Mtot = Mb + Ms;
  const int nptot = NPIX*9;
  const int nseg_max = Mtot + nptot/SEG + 2;

  char* wcur = (char*)d_ws;
  auto alloc = [&](size_t bytes) -> void* {
    void* p = (void*)wcur;
    wcur += (bytes + 63) & ~(size_t)63;
    return p;
  };
  __half* Qh     = (__half*)alloc((size_t)NPIX*QSH*2);
  __half* Uh     = (__half*)alloc((size_t)NPIX*USH*2);
  __half* vAb    = (__half*)alloc((size_t)(Mb+1)*VSH*2);
  __half* vBb    = (__half*)alloc((size_t)(Mb+1)*VSH*2);
  __half* vAs    = (__half*)alloc((size_t)(Ms+1)*VSH*2);
  __half* vBs    = (__half*)alloc((size_t)(Ms+1)*VSH*2);
  int*   start   = (int*)alloc((size_t)(Mtot+1)*4);
  int*   cur     = (int*)alloc((size_t)Mtot*4);
  int*   segstart= (int*)alloc((size_t)(Mtot+1)*4);
  int*   seg_m   = (int*)alloc((size_t)nseg_max*4);
  unsigned int* pw = (unsigned int*)alloc((size_t)nptot*4);
  float* partials= (float*)alloc((size_t)nseg_max*NCH2*4);
  int*   bsum    = (int*)alloc((size_t)(Mtot/256 + 3)*4);

  const int TB = 256;
  auto blocks = [](long long n){ return (int)((n + 255)/256); };
  const int nbM = blocks(Mtot);

  // ---- build unified CSR (slab order) ----
  hipMemsetAsync(cur, 0, (size_t)Mtot*sizeof(int), stream);
  count_fused_kernel<<<blocks(nptot), TB, 0, stream>>>(os_b, os_s, cur, nptot, Mb);
  scan_block_kernel<<<nbM, 256, 0, stream>>>(cur, start, bsum, Mtot);
  scan_sums_kernel<<<1, 256, 0, stream>>>(bsum, nbM);
  scan_add_kernel<<<blocks(Mtot+1), TB, 0, stream>>>(start, bsum, Mtot, nbM);
  hipMemsetAsync(cur, 0, (size_t)Mtot*sizeof(int), stream);
  fill_fused_kernel<<<blocks(nptot), TB, 0, stream>>>(os_b, ws_b, os_s, ws_s,
                                                      start, cur, pw, nptot, Mb);

  // ---- segment table (reuse cur as segcnt) ----
  nseg_kernel<<<nbM, TB, 0, stream>>>(start, cur, Mtot);
  scan_block_kernel<<<nbM, 256, 0, stream>>>(cur, segstart, bsum, Mtot);
  scan_sums_kernel<<<1, 256, 0, stream>>>(bsum, nbM);
  scan_add_kernel<<<blocks(Mtot+1), TB, 0, stream>>>(segstart, bsum, Mtot, nbM);
  seg_fill_kernel<<<nbM, TB, 0, stream>>>(segstart, seg_m, Mtot);

  // ---- zero sentinel row 0 of value buffers ----
  hipMemsetAsync(vAb, 0, VSH*2, stream);
  hipMemsetAsync(vBb, 0, VSH*2, stream);
  hipMemsetAsync(vAs, 0, VSH*2, stream);
  hipMemsetAsync(vBs, 0, VSH*2, stream);

  softmax_init_kernel<<<blocks(NPIX), TB, 0, stream>>>(U, Qh, Uh);

  for (int it = 0; it < 5; ++it) {
    gather_seg_kernel<<<blocks((long long)nseg_max*64), TB, 0, stream>>>(
        Qh, start, segstart, seg_m, pw, partials, Mtot);
    combine_kernel<<<blocks((long long)Mtot*NCH2), TB, 0, stream>>>(
        partials, segstart, vAb, vAs, Mb, Mtot);
    __half* ab = vAb; __half* bb = vBb;
    __half* as = vAs; __half* bs = vBs;
    for (int j = 0; j < 6; ++j) {
      int ms = (j < 3) ? Ms : 0;
      blurH_fused_kernel<<<blocks((long long)(Mb + ms)*11), TB, 0, stream>>>(
          ab, bb, bn_b + (size_t)j*Mb*2, Mb, as, bs, bn_s + (size_t)j*Ms*2, ms);
      { __half* t = ab; ab = bb; bb = t; }
      if (j < 3) { __half* t = as; as = bs; bs = t; }
    }
    if (it == 4) {
      slice_combine_softmax_kernel<true><<<blocks(NPIX), TB, 0, stream>>>(
          Uh, ab, as, ws_b, os_b, ws_s, os_s, (float*)d_out, (__half*)nullptr);
    } else {
      slice_combine_softmax_kernel<false><<<blocks(NPIX), TB, 0, stream>>>(
          Uh, ab, as, ws_b, os_b, ws_s, os_s, (float*)nullptr, Qh);
    }
  }
}

// Round 8
// 484.353 us; speedup vs baseline: 1.0982x; 1.0982x over previous
//
#include <hip/hip_runtime.h>
#include <hip/hip_fp16.h>

#define NCH 21
#define NCH2 22         // 21 Q-channels + channel 21 = weight-sum (norm)
#define VSH 32          // value row stride in halves (64B line)
#define QSH 32          // Q row stride in halves (64B line)
#define USH 24          // -U row stride in halves (48B, 16B-aligned)
#define NPIX (512*512)  // 2^18
#define DECODE (1.0f/(16383.f*128.f))

// ---------------- wave-aggregated atomic rank ----------------
__device__ __forceinline__ int wave_rank_atomic(int m, bool valid, int* __restrict__ cur) {
  int lane = threadIdx.x & 63;
  unsigned long long todo = __ballot(valid);
  int out = 0;
  while (todo) {
    int leader = __ffsll((unsigned long long)todo) - 1;
    int lm = __shfl(m, leader);
    unsigned long long match = __ballot(valid && (m == lm));
    int cnt = __popcll(match);
    int b = 0;
    if (lane == leader) b = atomicAdd(&cur[lm], cnt);
    b = __shfl(b, leader);
    if (valid && (m == lm)) out = b + __popcll(match & ((1ull << lane) - 1ull));
    todo &= ~match;
  }
  return out;
}

// ---------------- unified CSR build (slab order: t = j*NPIX + n) ----------------

__global__ void count_fused_kernel(const int* __restrict__ os_b, const int* __restrict__ os_s,
                                   int* __restrict__ cnt, int nptot, int Mb) {
  int t = blockIdx.x*blockDim.x + threadIdx.x;
  bool valid = (t < nptot);
  int m = 0;
  if (valid) {
    if (t < 6*NPIX) { int j = t >> 18, n = t & (NPIX-1); m = os_b[n*6+j]; }
    else { int t2 = t - 6*NPIX; int j = t2 >> 18, n = t2 & (NPIX-1); m = Mb + os_s[n*3+j]; }
  }
  int lane = threadIdx.x & 63;
  unsigned long long todo = __ballot(valid);
  while (todo) {
    int leader = __ffsll((unsigned long long)todo) - 1;
    int lm = __shfl(m, leader);
    unsigned long long match = __ballot(valid && (m == lm));
    if (lane == leader) atomicAdd(&cnt[lm], __popcll(match));
    todo &= ~match;
  }
}

__global__ void scan_block_kernel(const int* __restrict__ cnt, int* __restrict__ excl,
                                  int* __restrict__ bsum, int M) {
  __shared__ int s[256];
  int i = blockIdx.x*256 + threadIdx.x;
  int v = (i < M) ? cnt[i] : 0;
  s[threadIdx.x] = v;
  __syncthreads();
  for (int off = 1; off < 256; off <<= 1) {
    int t = (threadIdx.x >= off) ? s[threadIdx.x - off] : 0;
    __syncthreads();
    s[threadIdx.x] += t;
    __syncthreads();
  }
  if (i < M) excl[i] = s[threadIdx.x] - v;
  if (threadIdx.x == 255) bsum[blockIdx.x] = s[255];
}

__global__ void scan_sums_kernel(int* __restrict__ bsum, int nb) {
  __shared__ int s[256];
  __shared__ int carry;
  if (threadIdx.x == 0) carry = 0;
  __syncthreads();
  for (int base = 0; base < nb; base += 256) {
    int i = base + threadIdx.x;
    int v = (i < nb) ? bsum[i] : 0;
    s[threadIdx.x] = v;
    __syncthreads();
    for (int off = 1; off < 256; off <<= 1) {
      int t = (threadIdx.x >= off) ? s[threadIdx.x - off] : 0;
      __syncthreads();
      s[threadIdx.x] += t;
      __syncthreads();
    }
    if (i < nb) bsum[i] = s[threadIdx.x] - v + carry;
    int tot = s[255];
    __syncthreads();
    if (threadIdx.x == 0) carry += tot;
    __syncthreads();
  }
  if (threadIdx.x == 0) bsum[nb] = carry;   // grand total
}

__global__ void scan_add_kernel(int* __restrict__ excl, const int* __restrict__ bsum,
                                int M, int nb) {
  int i = blockIdx.x*blockDim.x + threadIdx.x;
  if (i < M) excl[i] += bsum[i >> 8];
  else if (i == M) excl[M] = bsum[nb];
}

__global__ void fill_fused_kernel(const int* __restrict__ os_b, const float* __restrict__ ws_b,
                                  const int* __restrict__ os_s, const float* __restrict__ ws_s,
                                  const int* __restrict__ start, int* __restrict__ cur,
                                  unsigned int* __restrict__ pw, int nptot, int Mb) {
  int t = blockIdx.x*blockDim.x + threadIdx.x;
  bool valid = (t < nptot);
  int m = 0, pix = 0; float w = 0.f;
  if (valid) {
    if (t < 6*NPIX) { int j = t >> 18, n = t & (NPIX-1); m = os_b[n*6+j]; pix = n; w = ws_b[n*6+j]; }
    else { int t2 = t - 6*NPIX; int j = t2 >> 18, n = t2 & (NPIX-1);
           m = Mb + os_s[n*3+j]; pix = n; w = ws_s[n*3+j]; }
  }
  int slot = wave_rank_atomic(m, valid, cur);
  if (valid) {
    int w14 = (int)(w * 16383.f + 0.5f);
    w14 = w14 < 0 ? 0 : (w14 > 16383 ? 16383 : w14);
    pw[start[m] + slot] = ((unsigned int)pix << 14) | (unsigned int)w14;
  }
}

// packed slice table: (os+1)<<12 | w12, slab layout sl[j*NPIX+n] (6 bilateral + 3 spatial)
__global__ void pack_slice_kernel(const int* __restrict__ os_b, const float* __restrict__ ws_b,
                                  const int* __restrict__ os_s, const float* __restrict__ ws_s,
                                  unsigned int* __restrict__ sl, int nptot) {
  int t = blockIdx.x*blockDim.x + threadIdx.x;
  if (t >= nptot) return;
  int o; float w;
  if (t < 6*NPIX) { int j = t >> 18, n = t & (NPIX-1); o = os_b[n*6+j] + 1; w = ws_b[n*6+j]; }
  else { int t2 = t - 6*NPIX; int j = t2 >> 18, n = t2 & (NPIX-1); o = os_s[n*3+j] + 1; w = ws_s[n*3+j]; }
  int w12 = (int)(w * 4095.f + 0.5f);
  w12 = w12 < 0 ? 0 : (w12 > 4095 ? 4095 : w12);
  sl[t] = ((unsigned int)o << 12) | (unsigned int)w12;
}

// ---------------- lattice ops ----------------

// gather splat, wave-per-lattice-point: 3 pair-groups x 21 channels + shfl reduce;
// channel 21 = weight sum (norm), rides along for free.
__global__ void gather_wave_kernel(const __half* __restrict__ Qh, const int* __restrict__ start,
                                   const unsigned int* __restrict__ pw,
                                   __half* __restrict__ valsB, __half* __restrict__ valsS,
                                   int Mb, int Mtot) {
  int wid = blockIdx.x*(blockDim.x >> 6) + (threadIdx.x >> 6);
  if (wid >= Mtot) return;
  int lane = threadIdx.x & 63;
  int pg = lane / 21;          // 0,1,2 (lane 63 idle)
  int c  = lane - pg*21;
  float s = 0.f, wsum = 0.f;
  int k1 = start[wid+1];
  if (pg < 3) {
    int k = start[wid] + pg;
    for (; k + 9 < k1; k += 12) {
      unsigned int a0 = pw[k], a1 = pw[k+3], a2 = pw[k+6], a3 = pw[k+9];
      float w0 = (float)(a0 & 16383u), w1 = (float)(a1 & 16383u);
      float w2 = (float)(a2 & 16383u), w3 = (float)(a3 & 16383u);
      s += w0 * __half2float(Qh[((size_t)(a0 >> 14) << 5) + c])
         + w1 * __half2float(Qh[((size_t)(a1 >> 14) << 5) + c])
         + w2 * __half2float(Qh[((size_t)(a2 >> 14) << 5) + c])
         + w3 * __half2float(Qh[((size_t)(a3 >> 14) << 5) + c]);
      wsum += w0 + w1 + w2 + w3;
    }
    for (; k < k1; k += 3) {
      unsigned int a = pw[k];
      float w = (float)(a & 16383u);
      s += w * __half2float(Qh[((size_t)(a >> 14) << 5) + c]);
      wsum += w;
    }
  }
  float s1 = __shfl(s, (lane + 21) & 63);
  float s2 = __shfl(s, (lane + 42) & 63);
  float wt = __shfl(wsum, 0) + __shfl(wsum, 21) + __shfl(wsum, 42);
  __half* row = (wid < Mb) ? (valsB + (size_t)(wid+1)*VSH)
                           : (valsS + (size_t)(wid-Mb+1)*VSH);
  if (lane < 21)       row[c]  = __float2half((s + s1 + s2) * DECODE);
  else if (lane == 21) row[21] = __float2half(wt * DECODE);
}

// blur on fp16 rows, half2 chunks (11 chunks = 22 channels), fp32 math
__global__ void blurH_fused_kernel(const __half* __restrict__ inB, __half* __restrict__ outB,
                                   const int* __restrict__ bnB, int Mb,
                                   const __half* __restrict__ inS, __half* __restrict__ outS,
                                   const int* __restrict__ bnS, int Ms) {
  int t = blockIdx.x*blockDim.x + threadIdx.x;
  const __half* in; __half* out; const int* bn; int i, j;
  int tb = Mb*11;
  if (t < tb) { i = t/11; j = t - i*11; in = inB; out = outB; bn = bnB; }
  else {
    int t2 = t - tb;
    if (t2 >= Ms*11) return;
    i = t2/11; j = t2 - i*11; in = inS; out = outS; bn = bnS;
  }
  int b0 = bn[2*i], b1 = bn[2*i+1];
  float2 a = __half22float2(((const __half2*)(in + (size_t)(i+1)*VSH))[j]);
  float2 x = __half22float2(((const __half2*)(in + (size_t)b0*VSH))[j]);
  float2 y = __half22float2(((const __half2*)(in + (size_t)b1*VSH))[j]);
  float2 o;
  o.x = a.x + 0.5f*(x.x + y.x);
  o.y = a.y + 0.5f*(x.y + y.y);
  ((__half2*)(out + (size_t)(i+1)*VSH))[j] = __float22half2_rn(o);
}

// ---------------- pixel-side kernels ----------------

__global__ void softmax_init_kernel(const float* __restrict__ U, __half* __restrict__ Qh,
                                    __half* __restrict__ Uh) {
  int n = blockIdx.x*blockDim.x + threadIdx.x;
  if (n >= NPIX) return;
  float l[NCH];
  float m = -3.4e38f;
  #pragma unroll
  for (int c = 0; c < NCH; ++c) {
    l[c] = -U[(size_t)n*NCH+c];
    Uh[(size_t)n*USH+c] = __float2half(l[c]);   // store negated U
    m = fmaxf(m, l[c]);
  }
  float s = 0.f;
  #pragma unroll
  for (int c = 0; c < NCH; ++c) { l[c] = expf(l[c]-m); s += l[c]; }
  float r = 1.0f/s;
  #pragma unroll
  for (int c = 0; c < NCH; ++c) Qh[(size_t)n*QSH+c] = __float2half(l[c]*r);
}

template<bool FINAL, bool PACKED>
__global__ void slice_combine_softmax_kernel(
    const __half* __restrict__ Uh,
    const __half* __restrict__ vb, const __half* __restrict__ vs,
    const unsigned int* __restrict__ sl,
    const float* __restrict__ ws_b, const int* __restrict__ os_b,
    const float* __restrict__ ws_s, const int* __restrict__ os_s,
    float* __restrict__ QoutF, __half* __restrict__ QoutH) {
  int n = blockIdx.x*blockDim.x + threadIdx.x;
  if (n >= NPIX) return;
  float l[NCH];
  #pragma unroll
  for (int c = 0; c < NCH; ++c) l[c] = __half2float(Uh[(size_t)n*USH+c]);
  float acc[NCH2];
  #pragma unroll
  for (int c = 0; c < NCH2; ++c) acc[c] = 0.f;
  #pragma unroll
  for (int j = 0; j < 6; ++j) {
    float w; const __half* v;
    if (PACKED) {
      unsigned int e = sl[(size_t)j*NPIX + n];
      w = (float)(e & 4095u);
      v = vb + ((size_t)(e >> 12) << 5);
    } else {
      w = ws_b[n*6+j];
      v = vb + (size_t)(os_b[n*6+j]+1)*VSH;
    }
    #pragma unroll
    for (int c = 0; c < NCH2; ++c) acc[c] += w*__half2float(v[c]);
  }
  float rb = 10.0f/(acc[NCH] + 1e-12f);
  #pragma unroll
  for (int c = 0; c < NCH; ++c) l[c] += rb*acc[c];
  #pragma unroll
  for (int c = 0; c < NCH2; ++c) acc[c] = 0.f;
  #pragma unroll
  for (int j = 0; j < 3; ++j) {
    float w; const __half* v;
    if (PACKED) {
      unsigned int e = sl[(size_t)(6+j)*NPIX + n];
      w = (float)(e & 4095u);
      v = vs + ((size_t)(e >> 12) << 5);
    } else {
      w = ws_s[n*3+j];
      v = vs + (size_t)(os_s[n*3+j]+1)*VSH;
    }
    #pragma unroll
    for (int c = 0; c < NCH2; ++c) acc[c] += w*__half2float(v[c]);
  }
  float rs = 3.0f/(acc[NCH] + 1e-12f);
  #pragma unroll
  for (int c = 0; c < NCH; ++c) l[c] += rs*acc[c];
  float m = -3.4e38f;
  #pragma unroll
  for (int c = 0; c < NCH; ++c) m = fmaxf(m, l[c]);
  float s = 0.f;
  #pragma unroll
  for (int c = 0; c < NCH; ++c) { l[c] = expf(l[c]-m); s += l[c]; }
  float r = 1.0f/s;
  if (FINAL) {
    #pragma unroll
    for (int c = 0; c < NCH; ++c) QoutF[(size_t)n*NCH+c] = l[c]*r;
  } else {
    #pragma unroll
    for (int c = 0; c < NCH; ++c) QoutH[(size_t)n*QSH+c] = __float2half(l[c]*r);
  }
}

// ---------------- host ----------------

extern "C" void kernel_launch(void* const* d_in, const int* in_sizes, int n_in,
                              void* d_out, int out_size, void* d_ws, size_t ws_size,
                              hipStream_t stream) {
  const float* U    = (const float*)d_in[0];
  const float* ws_b = (const float*)d_in[1];
  const float* ws_s = (const float*)d_in[2];
  const int*   os_b = (const int*)d_in[3];
  const int*   os_s = (const int*)d_in[4];
  const int*   bn_b = (const int*)d_in[5];
  const int*   bn_s = (const int*)d_in[6];
  const int Mb = in_sizes[5] / 12;
  const int Ms = in_sizes[6] / 6;
  const int Mtot = Mb + Ms;
  const int nptot = NPIX*9;
  const bool packed = (Mtot + 1) < (1 << 20);

  char* wcur = (char*)d_ws;
  auto alloc = [&](size_t bytes) -> void* {
    void* p = (void*)wcur;
    wcur += (bytes + 63) & ~(size_t)63;
    return p;
  };
  __half* Qh     = (__half*)alloc((size_t)NPIX*QSH*2);
  __half* Uh     = (__half*)alloc((size_t)NPIX*USH*2);
  __half* vAb    = (__half*)alloc((size_t)(Mb+1)*VSH*2);
  __half* vBb    = (__half*)alloc((size_t)(Mb+1)*VSH*2);
  __half* vAs    = (__half*)alloc((size_t)(Ms+1)*VSH*2);
  __half* vBs    = (__half*)alloc((size_t)(Ms+1)*VSH*2);
  int*   start   = (int*)alloc((size_t)(Mtot+1)*4);
  int*   cur     = (int*)alloc((size_t)Mtot*4);
  unsigned int* pw = (unsigned int*)alloc((size_t)nptot*4);
  unsigned int* sl = (unsigned int*)alloc((size_t)nptot*4);
  int*   bsum    = (int*)alloc((size_t)(Mtot/256 + 3)*4);

  const int TB = 256;
  auto blocks = [](long long n){ return (int)((n + 255)/256); };
  const int nbM = blocks(Mtot);

  // ---- build unified CSR (slab order) ----
  hipMemsetAsync(cur, 0, (size_t)Mtot*sizeof(int), stream);
  count_fused_kernel<<<blocks(nptot), TB, 0, stream>>>(os_b, os_s, cur, nptot, Mb);
  scan_block_kernel<<<nbM, 256, 0, stream>>>(cur, start, bsum, Mtot);
  scan_sums_kernel<<<1, 256, 0, stream>>>(bsum, nbM);
  scan_add_kernel<<<blocks(Mtot+1), TB, 0, stream>>>(start, bsum, Mtot, nbM);
  hipMemsetAsync(cur, 0, (size_t)Mtot*sizeof(int), stream);
  fill_fused_kernel<<<blocks(nptot), TB, 0, stream>>>(os_b, ws_b, os_s, ws_s,
                                                      start, cur, pw, nptot, Mb);
  if (packed)
    pack_slice_kernel<<<blocks(nptot), TB, 0, stream>>>(os_b, ws_b, os_s, ws_s, sl, nptot);

  // ---- zero sentinel row 0 of value buffers ----
  hipMemsetAsync(vAb, 0, VSH*2, stream);
  hipMemsetAsync(vBb, 0, VSH*2, stream);
  hipMemsetAsync(vAs, 0, VSH*2, stream);
  hipMemsetAsync(vBs, 0, VSH*2, stream);

  softmax_init_kernel<<<blocks(NPIX), TB, 0, stream>>>(U, Qh, Uh);

  for (int it = 0; it < 5; ++it) {
    gather_wave_kernel<<<blocks((long long)Mtot*64), TB, 0, stream>>>(
        Qh, start, pw, vAb, vAs, Mb, Mtot);
    __half* ab = vAb; __half* bb = vBb;
    __half* as = vAs; __half* bs = vBs;
    for (int j = 0; j < 6; ++j) {
      int ms = (j < 3) ? Ms : 0;
      blurH_fused_kernel<<<blocks((long long)(Mb + ms)*11), TB, 0, stream>>>(
          ab, bb, bn_b + (size_t)j*Mb*2, Mb, as, bs, bn_s + (size_t)j*Ms*2, ms);
      { __half* t = ab; ab = bb; bb = t; }
      if (j < 3) { __half* t = as; as = bs; bs = t; }
    }
    // ab = final bilateral (vAb), as = final spatial (vBs)
    if (it == 4) {
      if (packed)
        slice_combine_softmax_kernel<true,true><<<blocks(NPIX), TB, 0, stream>>>(
            Uh, ab, as, sl, ws_b, os_b, ws_s, os_s, (float*)d_out, (__half*)nullptr);
      else
        slice_combine_softmax_kernel<true,false><<<blocks(NPIX), TB, 0, stream>>>(
            Uh, ab, as, sl, ws_b, os_b, ws_s, os_s, (float*)d_out, (__half*)nullptr);
    } else {
      if (packed)
        slice_combine_softmax_kernel<false,true><<<blocks(NPIX), TB, 0, stream>>>(
            Uh, ab, as, sl, ws_b, os_b, ws_s, os_s, (float*)nullptr, Qh);
      else
        slice_combine_softmax_kernel<false,false><<<blocks(NPIX), TB, 0, stream>>>(
            Uh, ab, as, sl, ws_b, os_b, ws_s, os_s, (float*)nullptr, Qh);
    }
  }
}

// Round 9
// 483.228 us; speedup vs baseline: 1.1008x; 1.0023x over previous
//
#include <hip/hip_runtime.h>
#include <hip/hip_fp16.h>

#define NCH 21
#define NCH2 22         // 21 Q-channels + channel 21 = weight-sum (norm)
#define VSH 32          // value row stride in halves (64B line)
#define QSH 32          // Q row stride in halves (64B line)
#define USH 24          // -U row stride in halves (48B, 16B-aligned)
#define NPIX (512*512)  // 2^18
#define DECODE12 (1.0f/(4095.f*128.f))
#define DECODE14 (1.0f/(16383.f*128.f))

// ---------------- wave-aggregated atomic rank ----------------
__device__ __forceinline__ int wave_rank_atomic(int m, bool valid, int* __restrict__ cur) {
  int lane = threadIdx.x & 63;
  unsigned long long todo = __ballot(valid);
  int out = 0;
  while (todo) {
    int leader = __ffsll((unsigned long long)todo) - 1;
    int lm = __shfl(m, leader);
    unsigned long long match = __ballot(valid && (m == lm));
    int cnt = __popcll(match);
    int b = 0;
    if (lane == leader) b = atomicAdd(&cur[lm], cnt);
    b = __shfl(b, leader);
    if (valid && (m == lm)) out = b + __popcll(match & ((1ull << lane) - 1ull));
    todo &= ~match;
  }
  return out;
}

// ---------------- build passes (slab order: t = j*NPIX + n) ----------------

// ONE pass over os/ws: writes packed slice table sl[t] = (m_unified+1)<<12 | w12
// AND does wave-aggregated count atomics into cnt.
__global__ void pack_count_kernel(const int* __restrict__ os_b, const float* __restrict__ ws_b,
                                  const int* __restrict__ os_s, const float* __restrict__ ws_s,
                                  unsigned int* __restrict__ sl, int* __restrict__ cnt,
                                  int nptot, int Mb) {
  int t = blockIdx.x*blockDim.x + threadIdx.x;
  bool valid = (t < nptot);
  int m = 0; float w = 0.f;
  if (valid) {
    if (t < 6*NPIX) { int j = t >> 18, n = t & (NPIX-1); m = os_b[n*6+j]; w = ws_b[n*6+j]; }
    else { int t2 = t - 6*NPIX; int j = t2 >> 18, n = t2 & (NPIX-1);
           m = Mb + os_s[n*3+j]; w = ws_s[n*3+j]; }
    int w12 = (int)(w * 4095.f + 0.5f);
    w12 = w12 < 0 ? 0 : (w12 > 4095 ? 4095 : w12);
    sl[t] = ((unsigned int)(m+1) << 12) | (unsigned int)w12;
  }
  int lane = threadIdx.x & 63;
  unsigned long long todo = __ballot(valid);
  while (todo) {
    int leader = __ffsll((unsigned long long)todo) - 1;
    int lm = __shfl(m, leader);
    unsigned long long match = __ballot(valid && (m == lm));
    if (lane == leader) atomicAdd(&cnt[lm], __popcll(match));
    todo &= ~match;
  }
}

// fallback (Mtot too big to pack): plain count from os
__global__ void count_fused_kernel(const int* __restrict__ os_b, const int* __restrict__ os_s,
                                   int* __restrict__ cnt, int nptot, int Mb) {
  int t = blockIdx.x*blockDim.x + threadIdx.x;
  bool valid = (t < nptot);
  int m = 0;
  if (valid) {
    if (t < 6*NPIX) { int j = t >> 18, n = t & (NPIX-1); m = os_b[n*6+j]; }
    else { int t2 = t - 6*NPIX; int j = t2 >> 18, n = t2 & (NPIX-1); m = Mb + os_s[n*3+j]; }
  }
  int lane = threadIdx.x & 63;
  unsigned long long todo = __ballot(valid);
  while (todo) {
    int leader = __ffsll((unsigned long long)todo) - 1;
    int lm = __shfl(m, leader);
    unsigned long long match = __ballot(valid && (m == lm));
    if (lane == leader) atomicAdd(&cnt[lm], __popcll(match));
    todo &= ~match;
  }
}

__global__ void scan_block_kernel(const int* __restrict__ cnt, int* __restrict__ excl,
                                  int* __restrict__ bsum, int M) {
  __shared__ int s[256];
  int i = blockIdx.x*256 + threadIdx.x;
  int v = (i < M) ? cnt[i] : 0;
  s[threadIdx.x] = v;
  __syncthreads();
  for (int off = 1; off < 256; off <<= 1) {
    int t = (threadIdx.x >= off) ? s[threadIdx.x - off] : 0;
    __syncthreads();
    s[threadIdx.x] += t;
    __syncthreads();
  }
  if (i < M) excl[i] = s[threadIdx.x] - v;
  if (threadIdx.x == 255) bsum[blockIdx.x] = s[255];
}

__global__ void scan_sums_kernel(int* __restrict__ bsum, int nb) {
  __shared__ int s[256];
  __shared__ int carry;
  if (threadIdx.x == 0) carry = 0;
  __syncthreads();
  for (int base = 0; base < nb; base += 256) {
    int i = base + threadIdx.x;
    int v = (i < nb) ? bsum[i] : 0;
    s[threadIdx.x] = v;
    __syncthreads();
    for (int off = 1; off < 256; off <<= 1) {
      int t = (threadIdx.x >= off) ? s[threadIdx.x - off] : 0;
      __syncthreads();
      s[threadIdx.x] += t;
      __syncthreads();
    }
    if (i < nb) bsum[i] = s[threadIdx.x] - v + carry;
    int tot = s[255];
    __syncthreads();
    if (threadIdx.x == 0) carry += tot;
    __syncthreads();
  }
  if (threadIdx.x == 0) bsum[nb] = carry;
}

__global__ void scan_add_kernel(int* __restrict__ excl, const int* __restrict__ bsum,
                                int M, int nb) {
  int i = blockIdx.x*blockDim.x + threadIdx.x;
  if (i < M) excl[i] += bsum[i >> 8];
  else if (i == M) excl[M] = bsum[nb];
}

// packed fill: reads sl only; pw[k] = pix<<12 | w12
__global__ void fill_packed_kernel(const unsigned int* __restrict__ sl,
                                   const int* __restrict__ start, int* __restrict__ cur,
                                   unsigned int* __restrict__ pw, int nptot) {
  int t = blockIdx.x*blockDim.x + threadIdx.x;
  bool valid = (t < nptot);
  int m = 0; unsigned int e = 0;
  if (valid) {
    e = sl[t];
    m = (int)(e >> 12) - 1;
  }
  int slot = wave_rank_atomic(m, valid, cur);
  if (valid) {
    unsigned int pix = (unsigned int)(t & (NPIX-1));
    pw[start[m] + slot] = (pix << 12) | (e & 4095u);
  }
}

// fallback fill from os/ws: pw[k] = pix<<14 | w14
__global__ void fill_fused_kernel(const int* __restrict__ os_b, const float* __restrict__ ws_b,
                                  const int* __restrict__ os_s, const float* __restrict__ ws_s,
                                  const int* __restrict__ start, int* __restrict__ cur,
                                  unsigned int* __restrict__ pw, int nptot, int Mb) {
  int t = blockIdx.x*blockDim.x + threadIdx.x;
  bool valid = (t < nptot);
  int m = 0, pix = 0; float w = 0.f;
  if (valid) {
    if (t < 6*NPIX) { int j = t >> 18, n = t & (NPIX-1); m = os_b[n*6+j]; pix = n; w = ws_b[n*6+j]; }
    else { int t2 = t - 6*NPIX; int j = t2 >> 18, n = t2 & (NPIX-1);
           m = Mb + os_s[n*3+j]; pix = n; w = ws_s[n*3+j]; }
  }
  int slot = wave_rank_atomic(m, valid, cur);
  if (valid) {
    int w14 = (int)(w * 16383.f + 0.5f);
    w14 = w14 < 0 ? 0 : (w14 > 16383 ? 16383 : w14);
    pw[start[m] + slot] = ((unsigned int)pix << 14) | (unsigned int)w14;
  }
}

// ---------------- lattice ops ----------------

// gather splat, wave-per-lattice-point: 3 pair-groups x 21 channels + shfl reduce;
// channel 21 = weight sum (norm), rides along for free.
template<int WBITS>
__global__ void gather_wave_kernel(const __half* __restrict__ Qh, const int* __restrict__ start,
                                   const unsigned int* __restrict__ pw,
                                   __half* __restrict__ valsB, __half* __restrict__ valsS,
                                   int Mb, int Mtot, float decode) {
  const unsigned int WMASK = (1u << WBITS) - 1u;
  int wid = blockIdx.x*(blockDim.x >> 6) + (threadIdx.x >> 6);
  if (wid >= Mtot) return;
  int lane = threadIdx.x & 63;
  int pg = lane / 21;          // 0,1,2 (lane 63 idle)
  int c  = lane - pg*21;
  float s = 0.f, wsum = 0.f;
  int k1 = start[wid+1];
  if (pg < 3) {
    int k = start[wid] + pg;
    for (; k + 9 < k1; k += 12) {
      unsigned int a0 = pw[k], a1 = pw[k+3], a2 = pw[k+6], a3 = pw[k+9];
      float w0 = (float)(a0 & WMASK), w1 = (float)(a1 & WMASK);
      float w2 = (float)(a2 & WMASK), w3 = (float)(a3 & WMASK);
      s += w0 * __half2float(Qh[((size_t)(a0 >> WBITS) << 5) + c])
         + w1 * __half2float(Qh[((size_t)(a1 >> WBITS) << 5) + c])
         + w2 * __half2float(Qh[((size_t)(a2 >> WBITS) << 5) + c])
         + w3 * __half2float(Qh[((size_t)(a3 >> WBITS) << 5) + c]);
      wsum += w0 + w1 + w2 + w3;
    }
    for (; k < k1; k += 3) {
      unsigned int a = pw[k];
      float w = (float)(a & WMASK);
      s += w * __half2float(Qh[((size_t)(a >> WBITS) << 5) + c]);
      wsum += w;
    }
  }
  float s1 = __shfl(s, (lane + 21) & 63);
  float s2 = __shfl(s, (lane + 42) & 63);
  float wt = __shfl(wsum, 0) + __shfl(wsum, 21) + __shfl(wsum, 42);
  __half* row = (wid < Mb) ? (valsB + (size_t)(wid+1)*VSH)
                           : (valsS + (size_t)(wid-Mb+1)*VSH);
  if (lane < 21)       row[c]  = __float2half((s + s1 + s2) * decode);
  else if (lane == 21) row[21] = __float2half(wt * decode);
}

// blur on fp16 rows, half2 chunks (11 chunks = 22 channels), fp32 math
__global__ void blurH_fused_kernel(const __half* __restrict__ inB, __half* __restrict__ outB,
                                   const int* __restrict__ bnB, int Mb,
                                   const __half* __restrict__ inS, __half* __restrict__ outS,
                                   const int* __restrict__ bnS, int Ms) {
  int t = blockIdx.x*blockDim.x + threadIdx.x;
  const __half* in; __half* out; const int* bn; int i, j;
  int tb = Mb*11;
  if (t < tb) { i = t/11; j = t - i*11; in = inB; out = outB; bn = bnB; }
  else {
    int t2 = t - tb;
    if (t2 >= Ms*11) return;
    i = t2/11; j = t2 - i*11; in = inS; out = outS; bn = bnS;
  }
  int b0 = bn[2*i], b1 = bn[2*i+1];
  float2 a = __half22float2(((const __half2*)(in + (size_t)(i+1)*VSH))[j]);
  float2 x = __half22float2(((const __half2*)(in + (size_t)b0*VSH))[j]);
  float2 y = __half22float2(((const __half2*)(in + (size_t)b1*VSH))[j]);
  float2 o;
  o.x = a.x + 0.5f*(x.x + y.x);
  o.y = a.y + 0.5f*(x.y + y.y);
  ((__half2*)(out + (size_t)(i+1)*VSH))[j] = __float22half2_rn(o);
}

// ---------------- pixel-side kernels ----------------

__global__ void softmax_init_kernel(const float* __restrict__ U, __half* __restrict__ Qh,
                                    __half* __restrict__ Uh) {
  int n = blockIdx.x*blockDim.x + threadIdx.x;
  if (n >= NPIX) return;
  float l[NCH];
  float m = -3.4e38f;
  #pragma unroll
  for (int c = 0; c < NCH; ++c) {
    l[c] = -U[(size_t)n*NCH+c];
    Uh[(size_t)n*USH+c] = __float2half(l[c]);   // store negated U
    m = fmaxf(m, l[c]);
  }
  float s = 0.f;
  #pragma unroll
  for (int c = 0; c < NCH; ++c) { l[c] = expf(l[c]-m); s += l[c]; }
  float r = 1.0f/s;
  #pragma unroll
  for (int c = 0; c < NCH; ++c) Qh[(size_t)n*QSH+c] = __float2half(l[c]*r);
}

// slice both lattices + combine + softmax; norm = channel-21 ratio (alphas cancel).
// PACKED: sl holds unified (m+1)<<12|w12; spatial rows come from vsShift = vs - Mb*VSH.
template<bool FINAL, bool PACKED>
__global__ void slice_combine_softmax_kernel(
    const __half* __restrict__ Uh,
    const __half* __restrict__ vb, const __half* __restrict__ vsShift,
    const unsigned int* __restrict__ sl,
    const float* __restrict__ ws_b, const int* __restrict__ os_b,
    const float* __restrict__ ws_s, const int* __restrict__ os_s,
    float* __restrict__ QoutF, __half* __restrict__ QoutH) {
  int n = blockIdx.x*blockDim.x + threadIdx.x;
  if (n >= NPIX) return;
  float l[NCH];
  #pragma unroll
  for (int c = 0; c < NCH; ++c) l[c] = __half2float(Uh[(size_t)n*USH+c]);
  float acc[NCH2];
  #pragma unroll
  for (int c = 0; c < NCH2; ++c) acc[c] = 0.f;
  #pragma unroll
  for (int j = 0; j < 6; ++j) {
    float w; const __half* v;
    if (PACKED) {
      unsigned int e = sl[(size_t)j*NPIX + n];
      w = (float)(e & 4095u);
      v = vb + ((size_t)(e >> 12) << 5);
    } else {
      w = ws_b[n*6+j];
      v = vb + (size_t)(os_b[n*6+j]+1)*VSH;
    }
    #pragma unroll
    for (int c = 0; c < NCH2; ++c) acc[c] += w*__half2float(v[c]);
  }
  float rb = 10.0f/(acc[NCH] + 1e-12f);
  #pragma unroll
  for (int c = 0; c < NCH; ++c) l[c] += rb*acc[c];
  #pragma unroll
  for (int c = 0; c < NCH2; ++c) acc[c] = 0.f;
  #pragma unroll
  for (int j = 0; j < 3; ++j) {
    float w; const __half* v;
    if (PACKED) {
      unsigned int e = sl[(size_t)(6+j)*NPIX + n];
      w = (float)(e & 4095u);
      v = vsShift + ((size_t)(e >> 12) << 5);
    } else {
      w = ws_s[n*3+j];
      v = vsShift + (size_t)(os_s[n*3+j]+1)*VSH;   // unpacked: vsShift == vs
    }
    #pragma unroll
    for (int c = 0; c < NCH2; ++c) acc[c] += w*__half2float(v[c]);
  }
  float rs = 3.0f/(acc[NCH] + 1e-12f);
  #pragma unroll
  for (int c = 0; c < NCH; ++c) l[c] += rs*acc[c];
  float m = -3.4e38f;
  #pragma unroll
  for (int c = 0; c < NCH; ++c) m = fmaxf(m, l[c]);
  float s = 0.f;
  #pragma unroll
  for (int c = 0; c < NCH; ++c) { l[c] = expf(l[c]-m); s += l[c]; }
  float r = 1.0f/s;
  if (FINAL) {
    #pragma unroll
    for (int c = 0; c < NCH; ++c) QoutF[(size_t)n*NCH+c] = l[c]*r;
  } else {
    #pragma unroll
    for (int c = 0; c < NCH; ++c) QoutH[(size_t)n*QSH+c] = __float2half(l[c]*r);
  }
}

// ---------------- host ----------------

extern "C" void kernel_launch(void* const* d_in, const int* in_sizes, int n_in,
                              void* d_out, int out_size, void* d_ws, size_t ws_size,
                              hipStream_t stream) {
  const float* U    = (const float*)d_in[0];
  const float* ws_b = (const float*)d_in[1];
  const float* ws_s = (const float*)d_in[2];
  const int*   os_b = (const int*)d_in[3];
  const int*   os_s = (const int*)d_in[4];
  const int*   bn_b = (const int*)d_in[5];
  const int*   bn_s = (const int*)d_in[6];
  const int Mb = in_sizes[5] / 12;
  const int Ms = in_sizes[6] / 6;
  const int Mtot = Mb + Ms;
  const int nptot = NPIX*9;
  const bool packed = (Mtot + 1) < (1 << 20);

  char* wcur = (char*)d_ws;
  auto alloc = [&](size_t bytes) -> void* {
    void* p = (void*)wcur;
    wcur += (bytes + 63) & ~(size_t)63;
    return p;
  };
  __half* Qh     = (__half*)alloc((size_t)NPIX*QSH*2);
  __half* Uh     = (__half*)alloc((size_t)NPIX*USH*2);
  __half* vAb    = (__half*)alloc((size_t)(Mb+1)*VSH*2);
  __half* vBb    = (__half*)alloc((size_t)(Mb+1)*VSH*2);
  __half* vAs    = (__half*)alloc((size_t)(Ms+1)*VSH*2);
  __half* vBs    = (__half*)alloc((size_t)(Ms+1)*VSH*2);
  int*   start   = (int*)alloc((size_t)(Mtot+1)*4);
  int*   cur     = (int*)alloc((size_t)Mtot*4);
  unsigned int* pw = (unsigned int*)alloc((size_t)nptot*4);
  unsigned int* sl = (unsigned int*)alloc((size_t)nptot*4);
  int*   bsum    = (int*)alloc((size_t)(Mtot/256 + 3)*4);

  const int TB = 256;
  auto blocks = [](long long n){ return (int)((n + 255)/256); };
  const int nbM = blocks(Mtot);

  // ---- build: pack+count (one pass), scan, fill ----
  hipMemsetAsync(cur, 0, (size_t)Mtot*sizeof(int), stream);
  if (packed)
    pack_count_kernel<<<blocks(nptot), TB, 0, stream>>>(os_b, ws_b, os_s, ws_s,
                                                        sl, cur, nptot, Mb);
  else
    count_fused_kernel<<<blocks(nptot), TB, 0, stream>>>(os_b, os_s, cur, nptot, Mb);
  scan_block_kernel<<<nbM, 256, 0, stream>>>(cur, start, bsum, Mtot);
  scan_sums_kernel<<<1, 256, 0, stream>>>(bsum, nbM);
  scan_add_kernel<<<blocks(Mtot+1), TB, 0, stream>>>(start, bsum, Mtot, nbM);
  hipMemsetAsync(cur, 0, (size_t)Mtot*sizeof(int), stream);
  if (packed)
    fill_packed_kernel<<<blocks(nptot), TB, 0, stream>>>(sl, start, cur, pw, nptot);
  else
    fill_fused_kernel<<<blocks(nptot), TB, 0, stream>>>(os_b, ws_b, os_s, ws_s,
                                                        start, cur, pw, nptot, Mb);

  // ---- zero sentinel row 0 of value buffers ----
  hipMemsetAsync(vAb, 0, VSH*2, stream);
  hipMemsetAsync(vBb, 0, VSH*2, stream);
  hipMemsetAsync(vAs, 0, VSH*2, stream);
  hipMemsetAsync(vBs, 0, VSH*2, stream);

  softmax_init_kernel<<<blocks(NPIX), TB, 0, stream>>>(U, Qh, Uh);

  for (int it = 0; it < 5; ++it) {
    if (packed)
      gather_wave_kernel<12><<<blocks((long long)Mtot*64), TB, 0, stream>>>(
          Qh, start, pw, vAb, vAs, Mb, Mtot, DECODE12);
    else
      gather_wave_kernel<14><<<blocks((long long)Mtot*64), TB, 0, stream>>>(
          Qh, start, pw, vAb, vAs, Mb, Mtot, DECODE14);
    __half* ab = vAb; __half* bb = vBb;
    __half* as = vAs; __half* bs = vBs;
    for (int j = 0; j < 6; ++j) {
      int ms = (j < 3) ? Ms : 0;
      blurH_fused_kernel<<<blocks((long long)(Mb + ms)*11), TB, 0, stream>>>(
          ab, bb, bn_b + (size_t)j*Mb*2, Mb, as, bs, bn_s + (size_t)j*Ms*2, ms);
      { __half* t = ab; ab = bb; bb = t; }
      if (j < 3) { __half* t = as; as = bs; bs = t; }
    }
    // ab = final bilateral (vAb), as = final spatial (vBs)
    const __half* vsArg = packed ? (as - (size_t)Mb*VSH) : as;
    if (it == 4) {
      if (packed)
        slice_combine_softmax_kernel<true,true><<<blocks(NPIX), TB, 0, stream>>>(
            Uh, ab, vsArg, sl, ws_b, os_b, ws_s, os_s, (float*)d_out, (__half*)nullptr);
      else
        slice_combine_softmax_kernel<true,false><<<blocks(NPIX), TB, 0, stream>>>(
            Uh, ab, vsArg, sl, ws_b, os_b, ws_s, os_s, (float*)d_out, (__half*)nullptr);
    } else {
      if (packed)
        slice_combine_softmax_kernel<false,true><<<blocks(NPIX), TB, 0, stream>>>(
            Uh, ab, vsArg, sl, ws_b, os_b, ws_s, os_s, (float*)nullptr, Qh);
      else
        slice_combine_softmax_kernel<false,false><<<blocks(NPIX), TB, 0, stream>>>(
            Uh, ab, vsArg, sl, ws_b, os_b, ws_s, os_s, (float*)nullptr, Qh);
    }
  }
}